// Round 10
// baseline (46.651 us; speedup 1.0000x reference)
//
#include <hip/hip_runtime.h>
#include <math.h>

#define J     29
#define CH    3
#define JC    87            // J*CH
#define E0    56
#define BATCH 256
#define T     1024
#define FPC   64            // frames per chunk (= lanes)
#define CPB   16            // chunks per block = T/FPC
#define CHUNK_BYTES (FPC*JC*4)   // 22272
#define LDSCH 22528         // LDS slot: chunk + 256B pad (absorbs over-read)
#define NBUF  5             // ring slots
#define DEPTH 4             // chunks prefetched ahead
#define WAVES 8
#define RPW   4             // rows per wave (rows 29..31 are padding)
#define NROUND 22           // 22 x 1KB staging rounds (last covers 768B + pad)
#define OVCAP 64            // per-wave overflow capacity (entries)

typedef const __attribute__((address_space(1))) void* gas_p;
typedef __attribute__((address_space(3))) void* las_p;

// stage one chunk: round r (1KB, 16B/lane aligned) issued by wave r%8.
// Lanes of round 21 that would read past the chunk read into the next chunk
// (in-bounds) and land in the LDS pad; for the very last chunk of the array
// the per-lane SOURCE is clamped (dest stays linear; pad bytes get dupes).
__device__ __forceinline__ void stage_chunk(const char* __restrict__ s,
                                            char* d, int lane, int wv,
                                            bool lastChunk) {
#pragma unroll
    for (int r0 = 0; r0 < 3; ++r0) {
        int r = wv + WAVES * r0;
        if (r < NROUND) {
            int goff = r * 1024 + lane * 16;
            if (lastChunk && goff > CHUNK_BYTES - 16) goff = CHUNK_BYTES - 16;
            __builtin_amdgcn_global_load_lds((gas_p)(s + goff),
                                             (las_p)(d + r * 1024), 16, 0, 0);
        }
    }
}
// per-chunk loads per wave: wv<6 -> 3, wv>=6 -> 2
// steady vmcnt = DEPTH * cnt = 12 (wv<6) / 8 (wv>=6)

__global__ __launch_bounds__(512)
void gcn_fused(const float* __restrict__ x,
               const int*   __restrict__ ei,
               const float* __restrict__ Wp,
               const float* __restrict__ bp,
               const float* __restrict__ fcW,
               const float* __restrict__ fcb,
               float* __restrict__ out) {
    __shared__ __align__(16) char ldsx[NBUF * LDSCH];  // 112640 B ring
    __shared__ int2  s_ov[WAVES * OVCAP];              // 4 KB overflow table
    __shared__ float h_s[32 * CH];

    int tid  = threadIdx.x;
    int lane = tid & 63;
    int wv   = tid >> 6;
    int rowbase = wv * RPW;                            // uniform 0,4,...,28

    const char* src = (const char*)x + (size_t)blockIdx.x * ((size_t)CPB * CHUNK_BYTES);
    const bool lastBlock = (blockIdx.x == BATCH - 1);

    // ---- fire the first DEPTH chunk stages immediately (fill the pipe) ----
#pragma unroll
    for (int c = 0; c < DEPTH; ++c)
        stage_chunk(src + (size_t)c * CHUNK_BYTES, ldsx + c * LDSCH, lane, wv, false);

    // ---- inline prep: build normalized-adjacency rows in registers --------
    // (overlapped with the staging flight; extra loads only make counted
    //  vmcnt waits conservative — safe)
    float dinv = 0.f;
    if (lane < J) {
        int d = 1;  // self loop
        for (int e = 0; e < E0; ++e) d += (ei[E0 + e] == lane) ? 1 : 0;
        dinv = rsqrtf((float)d);
    }
    float mrow[RPW];
    int   prx[RPW][4];
    float prv[RPW][4];
    int ovn = 0;                                       // wave-uniform
#pragma unroll
    for (int R = 0; R < RPW; ++R) {
        int j = rowbase + R;
        float mv = 0.f;
        if (lane < J && j < J) {
            int cnt = 0;
            for (int e = 0; e < E0; ++e)
                cnt += (ei[e] == lane && ei[E0 + e] == j) ? 1 : 0;
            float dj = __shfl(dinv, j);
            mv = (float)cnt * dinv * dj;
            if (lane == j) mv += dinv * dinv;
        }
        mrow[R] = mv;
        unsigned long long mask = __ballot(mv != 0.f); // uniform
#pragma unroll
        for (int sl = 0; sl < 4; ++sl) {               // 4 static slots
            int pos = 0; float v = 0.f;
            if (mask) {
                pos = __ffsll(mask) - 1;
                v = __shfl(mrow[R], pos);
                mask &= mask - 1;
            }
            prx[R][sl] = pos * 12;
            prv[R][sl] = v;
        }
        while (mask) {                                 // rare overflow -> LDS
            int pos = __ffsll(mask) - 1;
            mask &= mask - 1;
            float v = __shfl(mrow[R], pos);
            if (lane == 0) {
                int2 pr; pr.x = (j << 16) | (pos * 12); pr.y = __float_as_int(v);
                s_ov[wv * OVCAP + ovn] = pr;
            }
            ++ovn;
        }
    }
    float sWv[9], sbv[CH];
#pragma unroll
    for (int i = 0; i < 9; ++i) sWv[i] = Wp[i];
#pragma unroll
    for (int i = 0; i < CH; ++i) sbv[i] = bp[i];
    asm volatile("s_waitcnt lgkmcnt(0)" ::: "memory"); // s_ov writes flushed

    float acc[RPW][CH];
#pragma unroll
    for (int r = 0; r < RPW; ++r)
#pragma unroll
        for (int c = 0; c < CH; ++c) acc[r][c] = 0.f;

    // ---- main loop: depth-4 ring, counted vmcnt, raw barriers -------------
    for (int c = 0; c < CPB; ++c) {
        asm volatile("" ::: "memory");
        __builtin_amdgcn_s_barrier();      // buffer (c+DEPTH)%NBUF now free
        asm volatile("" ::: "memory");

        if (c + DEPTH < CPB) {
            stage_chunk(src + (size_t)(c + DEPTH) * CHUNK_BYTES,
                        ldsx + ((c + DEPTH) % NBUF) * LDSCH, lane, wv,
                        lastBlock && (c + DEPTH == CPB - 1));
            if (wv < 6) asm volatile("s_waitcnt vmcnt(12)" ::: "memory");
            else        asm volatile("s_waitcnt vmcnt(8)"  ::: "memory");
        } else {
            asm volatile("s_waitcnt vmcnt(0)" ::: "memory");  // tail drain
        }

        asm volatile("" ::: "memory");
        __builtin_amdgcn_s_barrier();      // chunk c landed for ALL waves
        __builtin_amdgcn_sched_barrier(0);

        const char* xf = ldsx + (c % NBUF) * LDSCH + lane * (JC * 4);

        // phase 1: static 4-slot gather (3 x b32 per slot)
        float y[RPW][CH];
#pragma unroll
        for (int R = 0; R < RPW; ++R) {
            float a0 = 0.f, a1 = 0.f, a2 = 0.f;
#pragma unroll
            for (int sl = 0; sl < 4; ++sl) {
                float v = prv[R][sl];
                const float* q = (const float*)(xf + prx[R][sl]);
                a0 += v * q[0];
                a1 += v * q[1];
                a2 += v * q[2];
            }
            y[R][0] = a0; y[R][1] = a1; y[R][2] = a2;
        }
        // phase 2: overflow (runtime-outer, static-inner — proven shape)
        for (int e = 0; e < ovn; ++e) {
            int2 pr = s_ov[wv * OVCAP + e];           // uniform ds_read
            int row = pr.x >> 16;
            int off = pr.x & 0xFFFF;
            float v = __int_as_float(pr.y);
            const float* q = (const float*)(xf + off);
            float d0 = v * q[0], d1 = v * q[1], d2 = v * q[2];
#pragma unroll
            for (int R = 0; R < RPW; ++R)
                if (row == rowbase + R) { y[R][0] += d0; y[R][1] += d1; y[R][2] += d2; }
        }
        // phase 3: W, bias, ReLU, accumulate
#pragma unroll
        for (int R = 0; R < RPW; ++R)
#pragma unroll
            for (int ch = 0; ch < CH; ++ch) {
                float t = y[R][0] * sWv[0 * CH + ch]
                        + y[R][1] * sWv[1 * CH + ch]
                        + y[R][2] * sWv[2 * CH + ch]
                        + sbv[ch];
                acc[R][ch] += fmaxf(t, 0.f);
            }
    }

    // ---- epilogue: reduce 1024 frames, emit h and z for this batch --------
#pragma unroll
    for (int R = 0; R < RPW; ++R)
#pragma unroll
        for (int ch = 0; ch < CH; ++ch) {
            float v = acc[R][ch];
#pragma unroll
            for (int s = 1; s < 64; s <<= 1) v += __shfl_xor(v, s, 64);
            if (lane == 0 && (rowbase + R) < J) h_s[(rowbase + R) * CH + ch] = v;
        }
    __syncthreads();   // vmcnt already 0; safe drain

    int b = blockIdx.x;
    if (tid < JC) out[(size_t)b * JC + tid] = h_s[tid] * (1.0f / (float)T);
    if (tid < 2) {
        float a = fcb[tid];
        for (int r = 0; r < JC; ++r)
            a += h_s[r] * (1.0f / (float)T) * fcW[r * 2 + tid];
        out[(size_t)BATCH * JC + b * 2 + tid] = 1.0f / (1.0f + expf(-a));
    }
}

extern "C" void kernel_launch(void* const* d_in, const int* in_sizes, int n_in,
                              void* d_out, int out_size, void* d_ws, size_t ws_size,
                              hipStream_t stream) {
    const float* x   = (const float*)d_in[0];
    const int*   ei  = (const int*)d_in[1];
    const float* W   = (const float*)d_in[4];
    const float* bb  = (const float*)d_in[5];
    const float* fcW = (const float*)d_in[6];
    const float* fcb = (const float*)d_in[7];

    gcn_fused<<<BATCH, WAVES * 64, 0, stream>>>(x, ei, W, bb, fcW, fcb, (float*)d_out);
}